// Round 3
// baseline (109.438 us; speedup 1.0000x reference)
//
#include <hip/hip_runtime.h>
#include <math.h>

// ---------------------------------------------------------------------------
// CategoricalAwareTabularEncoder — design 4 (wave-specialized, 4-barrier)
// (resubmission — round 2 bench failed on GPU acquisition, not on the kernel)
//
// Key algebra (unchanged): pair-MLP layer-1 factorizes:
//   pairs(i,j)@W1 = emb_i@W1a + emb_j@W1b
//   U = emb@W1a + b1, V = emb@W1b, Hsum[d] = sum_{i<j} relu(U_i[d]+V_j[d]),
//   combo_sum = Hsum@W2 + P*b2.
//
// Design-4 changes vs design-3 (critical-path / interval reductions):
//  * Cluster-distance interval ELIMINATED: it only needs EMBS, so it now runs
//    concurrently with phase A via wave specialization (waves 0-7: phase A
//    with 8 tokens/wave; waves 8-15: distances, waves 8/9 take 2 centers).
//    One fewer interval + one fewer __syncthreads (5 -> 4 barriers).
//  * Phase A with 8 waves halves the redundant packed-weight LDS traffic
//    (weights are identical across waves): 16x(16 b128+16 b64) -> 8x.
//  * EMBT transposed copy dropped entirely; EMBS padded to stride 36 h2
//    (144 B rows, 16B-aligned) so cluster waves read their token row as
//    8x ds_read_b128 into registers (was 32 scalar b32 against EMBT).
//  * Softmax result written IN PLACE over the distance buffer (frees 640 u32,
//    keeps static LDS under 64 KB).
// ---------------------------------------------------------------------------

typedef _Float16 h2 __attribute__((ext_vector_type(2)));
typedef _Float16 h4 __attribute__((ext_vector_type(4)));
typedef _Float16 h8 __attribute__((ext_vector_type(8)));
union H4u { h4 v; h2 h[2]; };
union H8u { h8 v; h2 h[4]; };

constexpr int BATCH = 256;
constexpr int S = 64, D = 64, F = 10;
constexpr int NPAIR = S * (S - 1) / 2;  // 2016

// LDS map in 4-byte units (total 15744 u32 = 62976 B < 64 KB)
//   WUV  h8 [k4*64+d] {wu_lo,wu_hi,wv_lo,wv_hi}   @0     (4096 u32)
//   WF   h4 [k4*64+d] {wf_lo,wf_hi}               @4096  (2048 u32)
//   After phase A the weight region is dead -> aliased:
//     PART f32 [32 g][64 d] @0..2047 | FF f32 [64][10] @2048..2687
//     CS f32 @2752..2761
constexpr int EMBS = 6144;   // [s][k2] h2, stride 36 (2304 u32; 144 B rows, 16B-aligned)
constexpr int U2B  = 8448;   // [s][d2] h2, stride 32 (2048 u32)
constexpr int V2T  = 10496;  // [d2][j] h2, stride 66 (2112 u32)
constexpr int FHT  = 12608;  // [s][d2] h2, stride 34 (2176 u32)
constexpr int DI_F = 14784;  // f32 [64][10] distances; softmax overwrites in place (640)
constexpr int W2P  = 15424;  // [f*32+d2] h2 packed freq_w2 (320)
constexpr int PART_F = 0;
constexpr int FF_F   = 2048;
constexpr int CS_F   = 2752;

__device__ __forceinline__ h2 pk2(float a, float b) {
#if __has_builtin(__builtin_amdgcn_cvt_pkrtz)
  auto t = __builtin_amdgcn_cvt_pkrtz(a, b);
  return __builtin_bit_cast(h2, t);
#else
  h2 r; r.x = (_Float16)a; r.y = (_Float16)b; return r;
#endif
}

__device__ __forceinline__ float fdot2f(h2 a, h2 b, float c) {
#if __has_builtin(__builtin_amdgcn_fdot2)
  typedef __fp16 q2 __attribute__((ext_vector_type(2)));
  return __builtin_amdgcn_fdot2(__builtin_bit_cast(q2, a),
                                __builtin_bit_cast(q2, b), c, false);
#else
  return c + (float)a.x * (float)b.x + (float)a.y * (float)b.y;
#endif
}

__device__ __forceinline__ h2 hmax2z(h2 a) {  // elementwise max(a, 0)
#if __has_builtin(__builtin_elementwise_max)
  h2 z = {(_Float16)0, (_Float16)0};
  return __builtin_elementwise_max(a, z);
#else
  h2 r;
  r.x = a.x > (_Float16)0 ? a.x : (_Float16)0;
  r.y = a.y > (_Float16)0 ? a.y : (_Float16)0;
  return r;
#endif
}

// value of lane (l+1) for even lanes l, via quad_perm [1,1,3,3]
__device__ __forceinline__ float lane_up1(float v) {
#if __has_builtin(__builtin_amdgcn_update_dpp)
  int r = __builtin_amdgcn_update_dpp(0, __float_as_int(v), 0xF5, 0xF, 0xF, false);
  return __int_as_float(r);
#else
  return __shfl_down(v, 1, 64);
#endif
}

__global__ __launch_bounds__(1024, 4)
void cat_enc_kernel(const int*   __restrict__ ids,
                    const float* __restrict__ emb_table,
                    const float* __restrict__ comb_w1,
                    const float* __restrict__ comb_b1,
                    const float* __restrict__ comb_w2,
                    const float* __restrict__ comb_b2,
                    const float* __restrict__ freq_w1,
                    const float* __restrict__ freq_b1,
                    const float* __restrict__ freq_w2,
                    const float* __restrict__ freq_b2,
                    const float* __restrict__ centers,
                    const float* __restrict__ cat_freq,
                    const float* __restrict__ total_samples,
                    float*       __restrict__ out)
{
  __shared__ __align__(16) unsigned int ldsu[15744];
  h2*    ldsH = (h2*)ldsu;
  float* ldsf = (float*)ldsu;
  const int tid = threadIdx.x;
  const int b = blockIdx.x, bBase = b * S;

  // ---------------- stage: gather emb + pack weights ------------------------
  {
    // emb gather first: dependent-load chain (ids -> row), start it early
    int s = tid >> 4, q = tid & 15;
    int id = ids[bBase + s];
    float4 e4 = *(const float4*)(emb_table + (size_t)id * D + q * 4);
    H4u ep; ep.h[0] = pk2(e4.x, e4.y); ep.h[1] = pk2(e4.z, e4.w);
    *(h4*)&ldsH[EMBS + s * 36 + q * 2] = ep.v;   // single b64 write

    // weight pack: tid enumerates (k4 = tid>>6, dd = tid&63)
    {
      const int k4 = tid >> 6, dd = tid & 63;
      const float* s0p = comb_w1 + (k4 * 4) * D + dd;        // Wu cols
      const float* s1p = s0p + D * D;                        // Wv cols
      const float* s2p = freq_w1 + (k4 * 4) * D + dd;        // Wf cols
      h4* dst = (h4*)ldsu;
      H4u u0; u0.h[0] = pk2(s0p[0], s0p[D]); u0.h[1] = pk2(s0p[2 * D], s0p[3 * D]);
      H4u u1; u1.h[0] = pk2(s1p[0], s1p[D]); u1.h[1] = pk2(s1p[2 * D], s1p[3 * D]);
      H4u u2; u2.h[0] = pk2(s2p[0], s2p[D]); u2.h[1] = pk2(s2p[2 * D], s2p[3 * D]);
      dst[2 * tid]     = u0.v;     // WUV elem tid, u-half
      dst[2 * tid + 1] = u1.v;     // WUV elem tid, v-half
      dst[2048 + tid]  = u2.v;     // WF elem tid
    }
    if (tid < 320) {
      int f = tid >> 5, d2 = tid & 31;
      ldsH[W2P + tid] = pk2(freq_w2[(2 * d2) * F + f], freq_w2[(2 * d2 + 1) * F + f]);
    }
  }
  __syncthreads();

  // ------- interval 1: phase A (waves 0-7) || cluster dist (waves 8-15) -----
  {
    const int wv   = __builtin_amdgcn_readfirstlane((int)(tid >> 6));
    const int lane = tid & 63;
    if (wv < 8) {
      // ---- phase A: U,V,FH for 8 tokens per wave, lane = d ----
      const int d  = lane;
      const int s0 = wv * 8;
      const float invT = 1.0f / total_samples[0];
      const float b1d = comb_b1[d], fb1d = freq_b1[d], fw1L = freq_w1[D * D + d];
      float aU[8], aV[8], aF[8];
#pragma unroll
      for (int si = 0; si < 8; ++si) {
        int idv = __builtin_amdgcn_readfirstlane(ids[bBase + s0 + si]);
        aU[si] = b1d; aV[si] = 0.f;
        aF[si] = fmaf(cat_freq[idv] * invT, fw1L, fb1d);
      }
      const h8* WUVp = (const h8*)ldsu;           // elem (k4*64+d), 16 B
      const h4* WFp  = (const h4*)(ldsu + 4096);  // elem (k4*64+d), 8 B
#pragma unroll 2
      for (int k8 = 0; k8 < 8; ++k8) {
        H8u wa; wa.v = WUVp[(2 * k8) * 64 + d];       // ds_read_b128
        H8u wb; wb.v = WUVp[(2 * k8 + 1) * 64 + d];
        H4u fa; fa.v = WFp[(2 * k8) * 64 + d];        // ds_read_b64
        H4u fb; fb.v = WFp[(2 * k8 + 1) * 64 + d];
#pragma unroll
        for (int si = 0; si < 8; ++si) {
          H8u e; e.v = *(const h8*)&ldsH[EMBS + (s0 + si) * 36 + k8 * 4];  // b128 bcast
          aU[si] = fdot2f(e.h[0], wa.h[0], aU[si]);
          aU[si] = fdot2f(e.h[1], wa.h[1], aU[si]);
          aV[si] = fdot2f(e.h[0], wa.h[2], aV[si]);
          aV[si] = fdot2f(e.h[1], wa.h[3], aV[si]);
          aF[si] = fdot2f(e.h[0], fa.h[0], aF[si]);
          aF[si] = fdot2f(e.h[1], fa.h[1], aF[si]);
          aU[si] = fdot2f(e.h[2], wb.h[0], aU[si]);
          aU[si] = fdot2f(e.h[3], wb.h[1], aU[si]);
          aV[si] = fdot2f(e.h[2], wb.h[2], aV[si]);
          aV[si] = fdot2f(e.h[3], wb.h[3], aV[si]);
          aF[si] = fdot2f(e.h[2], fb.h[0], aF[si]);
          aF[si] = fdot2f(e.h[3], fb.h[1], aF[si]);
        }
      }
      // pack (d, d+1) pairs across even/odd lanes, store f16x2
      const bool evenl = ((d & 1) == 0);
      const int d2 = d >> 1;
#pragma unroll
      for (int si = 0; si < 8; ++si) {
        float un = lane_up1(aU[si]);
        float vn = lane_up1(aV[si]);
        float fh = fmaxf(aF[si], 0.f);
        float fn = lane_up1(fh);
        if (evenl) {
          int srow = s0 + si;
          ldsH[U2B + srow * 32 + d2] = pk2(aU[si], un);
          ldsH[V2T + d2 * 66 + srow] = pk2(aV[si], vn);  // transposed V
          ldsH[FHT + srow * 34 + d2] = pk2(fh, fn);
        }
      }
    } else {
      // ---- cluster distances: lane = token s; wave 8+c -> center c
      //      (waves 8,9 also take centers 8,9) ----
      const int s = lane;
      H8u er[8];
#pragma unroll
      for (int k8 = 0; k8 < 8; ++k8)
        er[k8].v = *(const h8*)&ldsH[EMBS + s * 36 + k8 * 4];  // ds_read_b128
      for (int cc = wv - 8; cc < 10; cc += 8) {
        const float* crow = centers + cc * D;  // uniform -> s_load
        float acc = 0.f;
#pragma unroll
        for (int k8 = 0; k8 < 8; ++k8) {
#pragma unroll
          for (int t = 0; t < 4; ++t) {
            const int k2 = k8 * 4 + t;
            float t0 = (float)er[k8].h[t].x - crow[2 * k2];
            float t1 = (float)er[k8].h[t].y - crow[2 * k2 + 1];
            acc = fmaf(t0, t0, fmaf(t1, t1, acc));
          }
        }
        ldsf[DI_F + s * 10 + cc] = sqrtf(acc);
      }
    }
  }
  __syncthreads();

  // ------- interval 2: freq_feat (waves 0-9) + softmax (wave 10) + phase B --
  {
    if (tid < 640) {
      int s = tid & 63;
      int f = __builtin_amdgcn_readfirstlane((int)(tid >> 6));  // wave = f
      float acc = freq_b2[f];
      const h8* wrow = (const h8*)&ldsH[W2P + f * 32];
#pragma unroll
      for (int d8 = 0; d8 < 4; ++d8) {
        H8u wf; wf.v = wrow[d8];                                  // b128 bcast
        H4u f0; f0.v = *(const h4*)&ldsH[FHT + s * 34 + d8 * 4];      // b64
        H4u f1; f1.v = *(const h4*)&ldsH[FHT + s * 34 + d8 * 4 + 2];  // b64
        acc = fdot2f(f0.h[0], wf.h[0], acc);
        acc = fdot2f(f0.h[1], wf.h[1], acc);
        acc = fdot2f(f1.h[0], wf.h[2], acc);
        acc = fdot2f(f1.h[1], wf.h[3], acc);
      }
      ldsf[FF_F + s * 10 + f] = acc;
    } else if (tid < 704) {
      int s = tid - 640;
      float dv[10], dmin = 1e30f;
#pragma unroll
      for (int c = 0; c < 10; ++c) { dv[c] = ldsf[DI_F + s * 10 + c]; dmin = fminf(dmin, dv[c]); }
      float p[10], sum = 0.f;
#pragma unroll
      for (int c = 0; c < 10; ++c) { p[c] = expf(dmin - dv[c]); sum += p[c]; }
      float rs = 1.0f / sum;
#pragma unroll
      for (int c = 0; c < 10; ++c) ldsf[DI_F + s * 10 + c] = p[c] * rs;  // in place
    }
  }

  // ------- phase B: Hsum partials, group g owns rows {g, 63-g} --------------
  {
    const int dg = tid & 31, g = tid >> 5;
    h2 u2a = ldsH[U2B + g * 32 + dg];
    h2 u2b = ldsH[U2B + (63 - g) * 32 + dg];
    h2 za = {(_Float16)0, (_Float16)0};
    h2 acA0 = za, acA1 = za, accb = za;
    const int jsplit = 64 - g;      // row-b active for j >= jsplit (never in head)
    int j = g + 1;
    if (j & 1) {                    // scalar head to even j
      h2 v2 = ldsH[V2T + dg * 66 + j];
      acA0 = acA0 + hmax2z(u2a + v2);
      ++j;
    }
#pragma unroll 4
    for (; j < 64; j += 2) {
      H4u v; v.v = *(const h4*)&ldsH[V2T + dg * 66 + j];   // b64: j, j+1
      acA0 = acA0 + hmax2z(u2a + v.h[0]);
      acA1 = acA1 + hmax2z(u2a + v.h[1]);
      if (j + 1 >= jsplit) {
        if (j >= jsplit) accb = accb + hmax2z(u2b + v.h[0]);
        accb = accb + hmax2z(u2b + v.h[1]);
      }
    }
    h2 at = acA0 + acA1 + accb;
    ldsf[PART_F + g * 64 + 2 * dg]     = (float)at.x;
    ldsf[PART_F + g * 64 + 2 * dg + 1] = (float)at.y;
  }
  __syncthreads();

  // ------- Hsum reduce + combo_sum fused (wave 0, butterfly) ----------------
  if (tid < 64) {
    float h = 0.f;
#pragma unroll
    for (int g2 = 0; g2 < 32; ++g2) h += ldsf[PART_F + g2 * 64 + tid];
    float csv = 0.f;
#pragma unroll
    for (int f = 0; f < 10; ++f) {
      float p = h * comb_w2[tid * F + f];
#pragma unroll
      for (int off = 1; off < 64; off <<= 1) p += __shfl_xor(p, off, 64);
      if (tid == f) csv = p;
    }
    if (tid < 10) ldsf[CS_F + tid] = fmaf(comb_b2[tid], (float)NPAIR, csv);
  }
  __syncthreads();

  // ------- epilogue ---------------------------------------------------------
  if (tid < 640) {
    int f = tid % 10;
    float val = (ldsf[FF_F + tid] + ldsf[CS_F + f] + ldsf[DI_F + tid])
              * (1.0f / (float)(NPAIR + 2));
    out[(size_t)b * 640 + tid] = val;
  }
}

extern "C" void kernel_launch(void* const* d_in, const int* in_sizes, int n_in,
                              void* d_out, int out_size, void* d_ws, size_t ws_size,
                              hipStream_t stream) {
  (void)in_sizes; (void)n_in; (void)d_ws; (void)ws_size; (void)out_size;
  const int*   ids        = (const int*)  d_in[0];
  const float* emb_table  = (const float*)d_in[1];
  const float* comb_w1    = (const float*)d_in[2];
  const float* comb_b1    = (const float*)d_in[3];
  const float* comb_w2    = (const float*)d_in[4];
  const float* comb_b2    = (const float*)d_in[5];
  const float* freq_w1    = (const float*)d_in[6];
  const float* freq_b1    = (const float*)d_in[7];
  const float* freq_w2    = (const float*)d_in[8];
  const float* freq_b2    = (const float*)d_in[9];
  const float* centers    = (const float*)d_in[10];
  const float* cat_freq   = (const float*)d_in[11];
  const float* total_samp = (const float*)d_in[12];
  float* out = (float*)d_out;

  hipLaunchKernelGGL(cat_enc_kernel, dim3(BATCH), dim3(1024), 0, stream,
                     ids, emb_table, comb_w1, comb_b1, comb_w2, comb_b2,
                     freq_w1, freq_b1, freq_w2, freq_b2, centers, cat_freq,
                     total_samp, out);
}

// Round 4
// 107.666 us; speedup vs baseline: 1.0165x; 1.0165x over previous
//
#include <hip/hip_runtime.h>
#include <math.h>

// ---------------------------------------------------------------------------
// CategoricalAwareTabularEncoder — design 5 (3-barrier, fused tail)
//
// Key algebra (unchanged): pair-MLP layer-1 factorizes:
//   pairs(i,j)@W1 = emb_i@W1a + emb_j@W1b
//   U = emb@W1a + b1, V = emb@W1b, Hsum[d] = sum_{i<j} relu(U_i[d]+V_j[d]),
//   combo_sum = Hsum@W2 + P*b2.
//
// Design-5 changes vs design-4 (serialization removal; kernel is latency-
// bound at VALUBusy~0.3%, HBM~2% — no HW roofline anywhere near):
//  * Tail fused into ONE interval: after the phase-B barrier, wave f (0..9)
//    reduces PART + butterflies its own CS[f], recomputes the 10-exp softmax
//    per lane, and stores out[s][f] directly.  Deletes: wave-10 softmax
//    block, CS and FF LDS round-trips, one __syncthreads, the epilogue
//    interval.  freq_feat row lives in a REGISTER (wave f is also the
//    epilogue wave for f).  4 -> 3 barriers.
//  * cat_freq gather moved into the staging phase (FRQ slot, 64 f32), so
//    interval 1 no longer begins with a dependent ids->cat_freq global chain.
//  * DI padded to stride 11 (gcd(11,32)=1) so the fused-tail per-lane
//    distance reads are bank-conflict-free.
// ---------------------------------------------------------------------------

typedef _Float16 h2 __attribute__((ext_vector_type(2)));
typedef _Float16 h4 __attribute__((ext_vector_type(4)));
typedef _Float16 h8 __attribute__((ext_vector_type(8)));
union H4u { h4 v; h2 h[2]; };
union H8u { h8 v; h2 h[4]; };

constexpr int BATCH = 256;
constexpr int S = 64, D = 64, F = 10;
constexpr int NPAIR = S * (S - 1) / 2;  // 2016

// LDS map in 4-byte units (total 15872 u32 = 63488 B < 64 KB)
//   WUV  h8 [k4*64+d] {wu_lo,wu_hi,wv_lo,wv_hi}   @0     (4096 u32)
//   WF   h4 [k4*64+d] {wf_lo,wf_hi}               @4096  (2048 u32)
//   After phase A the weight region is dead -> aliased:
//     PART f32 [32 g][64 d] @0..2047
constexpr int EMBS = 6144;   // [s][k2] h2, stride 36 (2304 u32; 144 B rows, 16B-aligned)
constexpr int U2B  = 8448;   // [s][d2] h2, stride 32 (2048 u32)
constexpr int V2T  = 10496;  // [d2][j] h2, stride 66 (2112 u32)
constexpr int FHT  = 12608;  // [s][d2] h2, stride 34 (2176 u32)
constexpr int DI_F = 14784;  // f32 [64][stride 11] raw distances (704)
constexpr int W2P  = 15488;  // [f*32+d2] h2 packed freq_w2 (320)
constexpr int FRQ  = 15808;  // f32 [64] cat_freq per token (64)
constexpr int PART_F = 0;

__device__ __forceinline__ h2 pk2(float a, float b) {
#if __has_builtin(__builtin_amdgcn_cvt_pkrtz)
  auto t = __builtin_amdgcn_cvt_pkrtz(a, b);
  return __builtin_bit_cast(h2, t);
#else
  h2 r; r.x = (_Float16)a; r.y = (_Float16)b; return r;
#endif
}

__device__ __forceinline__ float fdot2f(h2 a, h2 b, float c) {
#if __has_builtin(__builtin_amdgcn_fdot2)
  typedef __fp16 q2 __attribute__((ext_vector_type(2)));
  return __builtin_amdgcn_fdot2(__builtin_bit_cast(q2, a),
                                __builtin_bit_cast(q2, b), c, false);
#else
  return c + (float)a.x * (float)b.x + (float)a.y * (float)b.y;
#endif
}

__device__ __forceinline__ h2 hmax2z(h2 a) {  // elementwise max(a, 0)
#if __has_builtin(__builtin_elementwise_max)
  h2 z = {(_Float16)0, (_Float16)0};
  return __builtin_elementwise_max(a, z);
#else
  h2 r;
  r.x = a.x > (_Float16)0 ? a.x : (_Float16)0;
  r.y = a.y > (_Float16)0 ? a.y : (_Float16)0;
  return r;
#endif
}

// value of lane (l+1) for even lanes l, via quad_perm [1,1,3,3]
__device__ __forceinline__ float lane_up1(float v) {
#if __has_builtin(__builtin_amdgcn_update_dpp)
  int r = __builtin_amdgcn_update_dpp(0, __float_as_int(v), 0xF5, 0xF, 0xF, false);
  return __int_as_float(r);
#else
  return __shfl_down(v, 1, 64);
#endif
}

__global__ __launch_bounds__(1024, 4)
void cat_enc_kernel(const int*   __restrict__ ids,
                    const float* __restrict__ emb_table,
                    const float* __restrict__ comb_w1,
                    const float* __restrict__ comb_b1,
                    const float* __restrict__ comb_w2,
                    const float* __restrict__ comb_b2,
                    const float* __restrict__ freq_w1,
                    const float* __restrict__ freq_b1,
                    const float* __restrict__ freq_w2,
                    const float* __restrict__ freq_b2,
                    const float* __restrict__ centers,
                    const float* __restrict__ cat_freq,
                    const float* __restrict__ total_samples,
                    float*       __restrict__ out)
{
  __shared__ __align__(16) unsigned int ldsu[15872];
  h2*    ldsH = (h2*)ldsu;
  float* ldsf = (float*)ldsu;
  const int tid = threadIdx.x;
  const int b = blockIdx.x, bBase = b * S;
  float ffreg = 0.f;   // freq_feat[s=lane][f=wave] lives in a register (waves 0-9)

  // ---------------- stage: gather emb + freqs + pack weights ----------------
  {
    // emb gather first: dependent-load chain (ids -> row), start it early
    int s = tid >> 4, q = tid & 15;
    int id = ids[bBase + s];
    float4 e4 = *(const float4*)(emb_table + (size_t)id * D + q * 4);
    H4u ep; ep.h[0] = pk2(e4.x, e4.y); ep.h[1] = pk2(e4.z, e4.w);
    *(h4*)&ldsH[EMBS + s * 36 + q * 2] = ep.v;   // single b64 write
    if (q == 0) ldsf[FRQ + s] = cat_freq[id];    // hoisted out of interval 1

    // weight pack: tid enumerates (k4 = tid>>6, dd = tid&63)
    {
      const int k4 = tid >> 6, dd = tid & 63;
      const float* s0p = comb_w1 + (k4 * 4) * D + dd;        // Wu cols
      const float* s1p = s0p + D * D;                        // Wv cols
      const float* s2p = freq_w1 + (k4 * 4) * D + dd;        // Wf cols
      h4* dst = (h4*)ldsu;
      H4u u0; u0.h[0] = pk2(s0p[0], s0p[D]); u0.h[1] = pk2(s0p[2 * D], s0p[3 * D]);
      H4u u1; u1.h[0] = pk2(s1p[0], s1p[D]); u1.h[1] = pk2(s1p[2 * D], s1p[3 * D]);
      H4u u2; u2.h[0] = pk2(s2p[0], s2p[D]); u2.h[1] = pk2(s2p[2 * D], s2p[3 * D]);
      dst[2 * tid]     = u0.v;     // WUV elem tid, u-half
      dst[2 * tid + 1] = u1.v;     // WUV elem tid, v-half
      dst[2048 + tid]  = u2.v;     // WF elem tid
    }
    if (tid < 320) {
      int f = tid >> 5, d2 = tid & 31;
      ldsH[W2P + tid] = pk2(freq_w2[(2 * d2) * F + f], freq_w2[(2 * d2 + 1) * F + f]);
    }
  }
  __syncthreads();

  // ------- interval 1: phase A (waves 0-7) || cluster dist (waves 8-15) -----
  {
    const int wv   = __builtin_amdgcn_readfirstlane((int)(tid >> 6));
    const int lane = tid & 63;
    if (wv < 8) {
      // ---- phase A: U,V,FH for 8 tokens per wave, lane = d ----
      const int d  = lane;
      const int s0 = wv * 8;
      const float invT = 1.0f / total_samples[0];
      const float b1d = comb_b1[d], fb1d = freq_b1[d], fw1L = freq_w1[D * D + d];
      float aU[8], aV[8], aF[8];
#pragma unroll
      for (int si = 0; si < 8; ++si) {
        aU[si] = b1d; aV[si] = 0.f;
        aF[si] = fmaf(ldsf[FRQ + s0 + si] * invT, fw1L, fb1d);  // LDS broadcast
      }
      const h8* WUVp = (const h8*)ldsu;           // elem (k4*64+d), 16 B
      const h4* WFp  = (const h4*)(ldsu + 4096);  // elem (k4*64+d), 8 B
#pragma unroll 2
      for (int k8 = 0; k8 < 8; ++k8) {
        H8u wa; wa.v = WUVp[(2 * k8) * 64 + d];       // ds_read_b128
        H8u wb; wb.v = WUVp[(2 * k8 + 1) * 64 + d];
        H4u fa; fa.v = WFp[(2 * k8) * 64 + d];        // ds_read_b64
        H4u fb; fb.v = WFp[(2 * k8 + 1) * 64 + d];
#pragma unroll
        for (int si = 0; si < 8; ++si) {
          H8u e; e.v = *(const h8*)&ldsH[EMBS + (s0 + si) * 36 + k8 * 4];  // b128 bcast
          aU[si] = fdot2f(e.h[0], wa.h[0], aU[si]);
          aU[si] = fdot2f(e.h[1], wa.h[1], aU[si]);
          aV[si] = fdot2f(e.h[0], wa.h[2], aV[si]);
          aV[si] = fdot2f(e.h[1], wa.h[3], aV[si]);
          aF[si] = fdot2f(e.h[0], fa.h[0], aF[si]);
          aF[si] = fdot2f(e.h[1], fa.h[1], aF[si]);
          aU[si] = fdot2f(e.h[2], wb.h[0], aU[si]);
          aU[si] = fdot2f(e.h[3], wb.h[1], aU[si]);
          aV[si] = fdot2f(e.h[2], wb.h[2], aV[si]);
          aV[si] = fdot2f(e.h[3], wb.h[3], aV[si]);
          aF[si] = fdot2f(e.h[2], fb.h[0], aF[si]);
          aF[si] = fdot2f(e.h[3], fb.h[1], aF[si]);
        }
      }
      // pack (d, d+1) pairs across even/odd lanes, store f16x2
      const bool evenl = ((d & 1) == 0);
      const int d2 = d >> 1;
#pragma unroll
      for (int si = 0; si < 8; ++si) {
        float un = lane_up1(aU[si]);
        float vn = lane_up1(aV[si]);
        float fh = fmaxf(aF[si], 0.f);
        float fn = lane_up1(fh);
        if (evenl) {
          int srow = s0 + si;
          ldsH[U2B + srow * 32 + d2] = pk2(aU[si], un);
          ldsH[V2T + d2 * 66 + srow] = pk2(aV[si], vn);  // transposed V
          ldsH[FHT + srow * 34 + d2] = pk2(fh, fn);
        }
      }
    } else {
      // ---- cluster distances: lane = token s; wave 8+c -> center c
      //      (waves 8,9 also take centers 8,9) ----
      const int s = lane;
      H8u er[8];
#pragma unroll
      for (int k8 = 0; k8 < 8; ++k8)
        er[k8].v = *(const h8*)&ldsH[EMBS + s * 36 + k8 * 4];  // ds_read_b128
      for (int cc = wv - 8; cc < 10; cc += 8) {
        const float* crow = centers + cc * D;  // uniform -> s_load
        float acc = 0.f;
#pragma unroll
        for (int k8 = 0; k8 < 8; ++k8) {
#pragma unroll
          for (int t = 0; t < 4; ++t) {
            const int k2 = k8 * 4 + t;
            float t0 = (float)er[k8].h[t].x - crow[2 * k2];
            float t1 = (float)er[k8].h[t].y - crow[2 * k2 + 1];
            acc = fmaf(t0, t0, fmaf(t1, t1, acc));
          }
        }
        ldsf[DI_F + s * 11 + cc] = sqrtf(acc);   // stride 11: conflict-free reads
      }
    }
  }
  __syncthreads();

  // ------- interval 2: freq_feat into regs (waves 0-9) then phase B (all) ---
  {
    if (tid < 640) {
      int s = tid & 63;
      int f = __builtin_amdgcn_readfirstlane((int)(tid >> 6));  // wave = f
      float acc = freq_b2[f];
      const h8* wrow = (const h8*)&ldsH[W2P + f * 32];
#pragma unroll
      for (int d8 = 0; d8 < 4; ++d8) {
        H8u wf; wf.v = wrow[d8];                                  // b128 bcast
        H4u f0; f0.v = *(const h4*)&ldsH[FHT + s * 34 + d8 * 4];      // b64
        H4u f1; f1.v = *(const h4*)&ldsH[FHT + s * 34 + d8 * 4 + 2];  // b64
        acc = fdot2f(f0.h[0], wf.h[0], acc);
        acc = fdot2f(f0.h[1], wf.h[1], acc);
        acc = fdot2f(f1.h[0], wf.h[2], acc);
        acc = fdot2f(f1.h[1], wf.h[3], acc);
      }
      ffreg = acc;                       // stays in a register (no LDS round-trip)
    }
  }

  // ------- phase B: Hsum partials, group g owns rows {g, 63-g} --------------
  {
    const int dg = tid & 31, g = tid >> 5;
    h2 u2a = ldsH[U2B + g * 32 + dg];
    h2 u2b = ldsH[U2B + (63 - g) * 32 + dg];
    h2 za = {(_Float16)0, (_Float16)0};
    h2 acA0 = za, acA1 = za, accb = za;
    const int jsplit = 64 - g;      // row-b active for j >= jsplit (never in head)
    int j = g + 1;
    if (j & 1) {                    // scalar head to even j
      h2 v2 = ldsH[V2T + dg * 66 + j];
      acA0 = acA0 + hmax2z(u2a + v2);
      ++j;
    }
#pragma unroll 4
    for (; j < 64; j += 2) {
      H4u v; v.v = *(const h4*)&ldsH[V2T + dg * 66 + j];   // b64: j, j+1
      acA0 = acA0 + hmax2z(u2a + v.h[0]);
      acA1 = acA1 + hmax2z(u2a + v.h[1]);
      if (j + 1 >= jsplit) {
        if (j >= jsplit) accb = accb + hmax2z(u2b + v.h[0]);
        accb = accb + hmax2z(u2b + v.h[1]);
      }
    }
    h2 at = acA0 + acA1 + accb;
    ldsf[PART_F + g * 64 + 2 * dg]     = (float)at.x;
    ldsf[PART_F + g * 64 + 2 * dg + 1] = (float)at.y;
  }
  __syncthreads();

  // ------- fused tail (waves 0-9): reduce+combo_sum, softmax, store ---------
  // wave f: (1) lane=d reduces PART and butterflies CS[f];
  //         (2) lane=s recomputes softmax for its token and stores out[s][f].
  if (tid < 640) {
    const int f = __builtin_amdgcn_readfirstlane((int)(tid >> 6));
    const int l = tid & 63;
    // (1) Hsum reduce along l=d, then butterfly to CS[f] in every lane
    float h = 0.f;
#pragma unroll
    for (int g2 = 0; g2 < 32; ++g2) h += ldsf[PART_F + g2 * 64 + l];
    float p = h * comb_w2[l * F + f];
#pragma unroll
    for (int off = 1; off < 64; off <<= 1) p += __shfl_xor(p, off, 64);
    const float cs = fmaf(comb_b2[f], (float)NPAIR, p);
    // (2) per-lane softmax over the 10 raw distances for token s=l
    float dv[10], dmin = 1e30f;
#pragma unroll
    for (int c = 0; c < 10; ++c) { dv[c] = ldsf[DI_F + l * 11 + c]; dmin = fminf(dmin, dv[c]); }
    float sum = 0.f;
#pragma unroll
    for (int c = 0; c < 10; ++c) sum += expf(dmin - dv[c]);
    const float clu = expf(dmin - dv[f]) / sum;
    const float val = (ffreg + cs + clu) * (1.0f / (float)(NPAIR + 2));
    out[(size_t)b * 640 + l * 10 + f] = val;
  }
}

extern "C" void kernel_launch(void* const* d_in, const int* in_sizes, int n_in,
                              void* d_out, int out_size, void* d_ws, size_t ws_size,
                              hipStream_t stream) {
  (void)in_sizes; (void)n_in; (void)d_ws; (void)ws_size; (void)out_size;
  const int*   ids        = (const int*)  d_in[0];
  const float* emb_table  = (const float*)d_in[1];
  const float* comb_w1    = (const float*)d_in[2];
  const float* comb_b1    = (const float*)d_in[3];
  const float* comb_w2    = (const float*)d_in[4];
  const float* comb_b2    = (const float*)d_in[5];
  const float* freq_w1    = (const float*)d_in[6];
  const float* freq_b1    = (const float*)d_in[7];
  const float* freq_w2    = (const float*)d_in[8];
  const float* freq_b2    = (const float*)d_in[9];
  const float* centers    = (const float*)d_in[10];
  const float* cat_freq   = (const float*)d_in[11];
  const float* total_samp = (const float*)d_in[12];
  float* out = (float*)d_out;

  hipLaunchKernelGGL(cat_enc_kernel, dim3(BATCH), dim3(1024), 0, stream,
                     ids, emb_table, comb_w1, comb_b1, comb_w2, comb_b2,
                     freq_w1, freq_b1, freq_w2, freq_b2, centers, cat_freq,
                     total_samp, out);
}

// Round 5
// 105.097 us; speedup vs baseline: 1.0413x; 1.0244x over previous
//
#include <hip/hip_runtime.h>
#include <math.h>

// ---------------------------------------------------------------------------
// CategoricalAwareTabularEncoder — design 6 (MFMA phase A, 3-barrier)
//
// Key algebra (unchanged): pair-MLP layer-1 factorizes:
//   pairs(i,j)@W1 = emb_i@W1a + emb_j@W1b
//   U = emb@W1a + b1, V = emb@W1b, Hsum[d] = sum_{i<j} relu(U_i[d]+V_j[d]),
//   combo_sum = Hsum@W2 + P*b2.
//
// Design-6 changes vs design-5:
//  * Phase A (U = E@W1a, V = E@W1b, FH = relu(E@Wf + frq*wL + fb1)) is now
//    3 x (64x64x64) f16 MFMA: 96 x v_mfma_f32_16x16x32_f16 over 12 waves
//    (wave w: mat = w>>2, tile-row tr = w&3, sweeps 4 tile-cols), replacing
//    ~6100 wave v_dot2 instrs + ~770 LDS reads.  A-frag = 1 ds_read_b128
//    from EMBS (row-major, stride 36); B-frag = 2 ds_read_b64 from WT
//    (weights packed TRANSPOSED [d][k2], stride 34 u32 -> 8B aligned,
//    <=2-way banks).  k-slot mapping cancels (A,B use identical slot maps);
//    C/D layout col=lane&15, row=(lane>>4)*4+reg (HW-verified).
//  * Epilogues write the SAME U2B/V2T/FHT f16 layouts as design 5, so
//    phase B, freq_feat, softmax and tail are byte-identical.
//  * Cluster distances: waves 12-15 (2-3 centers each), register-held E rows.
//  * FRQ pre-scaled by 1/total_samples at stage.
// ---------------------------------------------------------------------------

typedef _Float16 h2 __attribute__((ext_vector_type(2)));
typedef _Float16 h4 __attribute__((ext_vector_type(4)));
typedef _Float16 h8 __attribute__((ext_vector_type(8)));
typedef float    f4 __attribute__((ext_vector_type(4)));
union H4u { h4 v; h2 h[2]; };
union H8u { h8 v; h2 h[4]; };
union H8q { h8 v; h4 q[2]; };

constexpr int BATCH = 256;
constexpr int S = 64, D = 64, F = 10;
constexpr int NPAIR = S * (S - 1) / 2;  // 2016

// LDS map in 4-byte units (total 16256 u32 = 65024 B <= 64 KB)
//   WT   h2 [mat][d][k2]: WuT@0, WvT@2176, WfT@4352; row stride 34 (6528)
//   After interval 1 WT is dead -> PART f32 [32 g][64 d] @0..2047 aliases it.
constexpr int WTMAT = 64 * 34;  // 2176 u32 per matrix
constexpr int EMBS = 6528;   // [s][k2] h2, stride 36 (2304; 144 B rows, 16B-aligned)
constexpr int U2B  = 8832;   // [s][d2] h2, stride 32 (2048)
constexpr int V2T  = 10880;  // [d2][j] h2, stride 66 (2112)
constexpr int FHT  = 12992;  // [s][d2] h2, stride 34 (2176)
constexpr int DI_F = 15168;  // f32 [64][stride 11] raw distances (704)
constexpr int W2P  = 15872;  // [f*32+d2] h2 packed freq_w2 (320)
constexpr int FRQ  = 16192;  // f32 [64] cat_freq/total_samples per token (64)
constexpr int PART_F = 0;

__device__ __forceinline__ h2 pk2(float a, float b) {
#if __has_builtin(__builtin_amdgcn_cvt_pkrtz)
  auto t = __builtin_amdgcn_cvt_pkrtz(a, b);
  return __builtin_bit_cast(h2, t);
#else
  h2 r; r.x = (_Float16)a; r.y = (_Float16)b; return r;
#endif
}

__device__ __forceinline__ float fdot2f(h2 a, h2 b, float c) {
#if __has_builtin(__builtin_amdgcn_fdot2)
  typedef __fp16 q2 __attribute__((ext_vector_type(2)));
  return __builtin_amdgcn_fdot2(__builtin_bit_cast(q2, a),
                                __builtin_bit_cast(q2, b), c, false);
#else
  return c + (float)a.x * (float)b.x + (float)a.y * (float)b.y;
#endif
}

__device__ __forceinline__ h2 hmax2z(h2 a) {  // elementwise max(a, 0)
#if __has_builtin(__builtin_elementwise_max)
  h2 z = {(_Float16)0, (_Float16)0};
  return __builtin_elementwise_max(a, z);
#else
  h2 r;
  r.x = a.x > (_Float16)0 ? a.x : (_Float16)0;
  r.y = a.y > (_Float16)0 ? a.y : (_Float16)0;
  return r;
#endif
}

// value of lane (l+1) for even lanes l, via quad_perm [1,1,3,3]
__device__ __forceinline__ float lane_up1(float v) {
#if __has_builtin(__builtin_amdgcn_update_dpp)
  int r = __builtin_amdgcn_update_dpp(0, __float_as_int(v), 0xF5, 0xF, 0xF, false);
  return __int_as_float(r);
#else
  return __shfl_down(v, 1, 64);
#endif
}

__global__ __launch_bounds__(1024, 4)
void cat_enc_kernel(const int*   __restrict__ ids,
                    const float* __restrict__ emb_table,
                    const float* __restrict__ comb_w1,
                    const float* __restrict__ comb_b1,
                    const float* __restrict__ comb_w2,
                    const float* __restrict__ comb_b2,
                    const float* __restrict__ freq_w1,
                    const float* __restrict__ freq_b1,
                    const float* __restrict__ freq_w2,
                    const float* __restrict__ freq_b2,
                    const float* __restrict__ centers,
                    const float* __restrict__ cat_freq,
                    const float* __restrict__ total_samples,
                    float*       __restrict__ out)
{
  __shared__ __align__(16) unsigned int ldsu[16256];
  h2*    ldsH = (h2*)ldsu;
  float* ldsf = (float*)ldsu;
  const int tid = threadIdx.x;
  const int b = blockIdx.x, bBase = b * S;
  float ffreg = 0.f;   // freq_feat[s=lane][f=wave] register (waves 0-9)

  // ---------------- stage: gather emb + freqs + pack W^T --------------------
  {
    // emb gather first: dependent-load chain (ids -> row), start it early
    int s = tid >> 4, q = tid & 15;
    int id = ids[bBase + s];
    float4 e4 = *(const float4*)(emb_table + (size_t)id * D + q * 4);
    H4u ep; ep.h[0] = pk2(e4.x, e4.y); ep.h[1] = pk2(e4.z, e4.w);
    *(h4*)&ldsH[EMBS + s * 36 + q * 2] = ep.v;   // single b64 write
    if (q == 0) ldsf[FRQ + s] = cat_freq[id] * (1.0f / total_samples[0]);

    // W^T pack: task -> (mat, d, kp): writes WT[mat][d][2kp..2kp+1] (b64)
#pragma unroll
    for (int it = 0; it < 3; ++it) {
      const int task = tid + it * 1024;
      const int m = task >> 10, r = task & 1023;
      const int d = r & 63, kp = r >> 6;               // kp in 0..15, k = 4*kp
      const float* src = ((m == 0) ? comb_w1
                        : (m == 1) ? comb_w1 + D * D
                                   : freq_w1) + (4 * kp) * D + d;
      const float w0 = src[0], w1 = src[D], w2v = src[2 * D], w3 = src[3 * D];
      H4u wp; wp.h[0] = pk2(w0, w1); wp.h[1] = pk2(w2v, w3);
      *(h4*)&ldsH[m * WTMAT + d * 34 + 2 * kp] = wp.v;
    }
    if (tid < 320) {
      int f = tid >> 5, d2 = tid & 31;
      ldsH[W2P + tid] = pk2(freq_w2[(2 * d2) * F + f], freq_w2[(2 * d2 + 1) * F + f]);
    }
  }
  __syncthreads();

  // ------- interval 1: MFMA phase A (waves 0-11) || cluster (waves 12-15) ---
  {
    const int wv   = __builtin_amdgcn_readfirstlane((int)(tid >> 6));
    const int lane = tid & 63;
    if (wv < 12) {
      const int mat = wv >> 2, tr = wv & 3;
      const int col = lane & 15, grp = lane >> 4;
      const int base = tr * 16 + grp * 4;     // C/D row base for this lane
      const int arow = tr * 16 + col;         // A row for this lane
      // A-frags: E[arow][k], k-slices 0..15 / 16..31 per (grp,j); b128 each
      h8 A0 = *(const h8*)&ldsH[EMBS + arow * 36 + grp * 4];
      h8 A1 = *(const h8*)&ldsH[EMBS + arow * 36 + 16 + grp * 4];
      const int wtm = mat * WTMAT;
      f4 acc[4];
#pragma unroll
      for (int tc = 0; tc < 4; ++tc) {
        const int brow = tc * 16 + col;       // B col (= WT row)
        H8q B0, B1;
        B0.q[0] = *(const h4*)&ldsH[wtm + brow * 34 + grp * 4];
        B0.q[1] = *(const h4*)&ldsH[wtm + brow * 34 + grp * 4 + 2];
        B1.q[0] = *(const h4*)&ldsH[wtm + brow * 34 + 16 + grp * 4];
        B1.q[1] = *(const h4*)&ldsH[wtm + brow * 34 + 16 + grp * 4 + 2];
        f4 c = {0.f, 0.f, 0.f, 0.f};
        c = __builtin_amdgcn_mfma_f32_16x16x32_f16(A0, B0.v, c, 0, 0, 0);
        c = __builtin_amdgcn_mfma_f32_16x16x32_f16(A1, B1.v, c, 0, 0, 0);
        acc[tc] = c;
      }
      const bool evenc = ((col & 1) == 0);
      if (mat == 0) {                         // U = E@W1a + b1 -> U2B [s][d2]
#pragma unroll
        for (int tc = 0; tc < 4; ++tc) {
          const float bv = comb_b1[tc * 16 + col];
          float v0 = acc[tc][0] + bv, v1 = acc[tc][1] + bv,
                v2 = acc[tc][2] + bv, v3 = acc[tc][3] + bv;
          float n0 = lane_up1(v0), n1 = lane_up1(v1),
                n2 = lane_up1(v2), n3 = lane_up1(v3);
          if (evenc) {
            const int d2 = tc * 8 + (col >> 1);
            ldsH[U2B + (base + 0) * 32 + d2] = pk2(v0, n0);
            ldsH[U2B + (base + 1) * 32 + d2] = pk2(v1, n1);
            ldsH[U2B + (base + 2) * 32 + d2] = pk2(v2, n2);
            ldsH[U2B + (base + 3) * 32 + d2] = pk2(v3, n3);
          }
        }
      } else if (mat == 1) {                  // V = E@W1b -> V2T [d2][j]
#pragma unroll
        for (int tc = 0; tc < 4; ++tc) {
          float v0 = acc[tc][0], v1 = acc[tc][1],
                v2 = acc[tc][2], v3 = acc[tc][3];
          float n0 = lane_up1(v0), n1 = lane_up1(v1),
                n2 = lane_up1(v2), n3 = lane_up1(v3);
          if (evenc) {
            const int d2 = tc * 8 + (col >> 1);
            H4u w01; w01.h[0] = pk2(v0, n0); w01.h[1] = pk2(v1, n1);
            *(h4*)&ldsH[V2T + d2 * 66 + base] = w01.v;       // rows j..j+1
            H4u w23; w23.h[0] = pk2(v2, n2); w23.h[1] = pk2(v3, n3);
            *(h4*)&ldsH[V2T + d2 * 66 + base + 2] = w23.v;   // rows j+2..j+3
          }
        }
      } else {                                // FH = relu(E@Wf + frq*wL + fb1)
        const f4 frq4 = *(const f4*)&ldsf[FRQ + base];
#pragma unroll
        for (int tc = 0; tc < 4; ++tc) {
          const int d = tc * 16 + col;
          const float fwv = freq_w1[D * D + d], fbv = freq_b1[d];
          float v0 = fmaxf(fmaf(frq4[0], fwv, acc[tc][0]) + fbv, 0.f);
          float v1 = fmaxf(fmaf(frq4[1], fwv, acc[tc][1]) + fbv, 0.f);
          float v2 = fmaxf(fmaf(frq4[2], fwv, acc[tc][2]) + fbv, 0.f);
          float v3 = fmaxf(fmaf(frq4[3], fwv, acc[tc][3]) + fbv, 0.f);
          float n0 = lane_up1(v0), n1 = lane_up1(v1),
                n2 = lane_up1(v2), n3 = lane_up1(v3);
          if (evenc) {
            const int d2 = tc * 8 + (col >> 1);
            ldsH[FHT + (base + 0) * 34 + d2] = pk2(v0, n0);
            ldsH[FHT + (base + 1) * 34 + d2] = pk2(v1, n1);
            ldsH[FHT + (base + 2) * 34 + d2] = pk2(v2, n2);
            ldsH[FHT + (base + 3) * 34 + d2] = pk2(v3, n3);
          }
        }
      }
    } else {
      // ---- cluster distances: lane = token s; waves 12-15, centers cc ----
      const int s = lane;
      H8u er[8];
#pragma unroll
      for (int k8 = 0; k8 < 8; ++k8)
        er[k8].v = *(const h8*)&ldsH[EMBS + s * 36 + k8 * 4];  // ds_read_b128
      for (int cc = wv - 12; cc < 10; cc += 4) {
        const float* crow = centers + cc * D;  // uniform -> s_load
        float acc = 0.f;
#pragma unroll
        for (int k8 = 0; k8 < 8; ++k8) {
#pragma unroll
          for (int t = 0; t < 4; ++t) {
            const int k2 = k8 * 4 + t;
            float t0 = (float)er[k8].h[t].x - crow[2 * k2];
            float t1 = (float)er[k8].h[t].y - crow[2 * k2 + 1];
            acc = fmaf(t0, t0, fmaf(t1, t1, acc));
          }
        }
        ldsf[DI_F + s * 11 + cc] = sqrtf(acc);   // stride 11: conflict-free
      }
    }
  }
  __syncthreads();

  // ------- interval 2: freq_feat into regs (waves 0-9) then phase B (all) ---
  {
    if (tid < 640) {
      int s = tid & 63;
      int f = __builtin_amdgcn_readfirstlane((int)(tid >> 6));  // wave = f
      float acc = freq_b2[f];
      const h8* wrow = (const h8*)&ldsH[W2P + f * 32];
#pragma unroll
      for (int d8 = 0; d8 < 4; ++d8) {
        H8u wf; wf.v = wrow[d8];                                  // b128 bcast
        H4u f0; f0.v = *(const h4*)&ldsH[FHT + s * 34 + d8 * 4];      // b64
        H4u f1; f1.v = *(const h4*)&ldsH[FHT + s * 34 + d8 * 4 + 2];  // b64
        acc = fdot2f(f0.h[0], wf.h[0], acc);
        acc = fdot2f(f0.h[1], wf.h[1], acc);
        acc = fdot2f(f1.h[0], wf.h[2], acc);
        acc = fdot2f(f1.h[1], wf.h[3], acc);
      }
      ffreg = acc;                       // stays in a register
    }
  }

  // ------- phase B: Hsum partials, group g owns rows {g, 63-g} --------------
  {
    const int dg = tid & 31, g = tid >> 5;
    h2 u2a = ldsH[U2B + g * 32 + dg];
    h2 u2b = ldsH[U2B + (63 - g) * 32 + dg];
    h2 za = {(_Float16)0, (_Float16)0};
    h2 acA0 = za, acA1 = za, accb = za;
    const int jsplit = 64 - g;      // row-b active for j >= jsplit (never in head)
    int j = g + 1;
    if (j & 1) {                    // scalar head to even j
      h2 v2 = ldsH[V2T + dg * 66 + j];
      acA0 = acA0 + hmax2z(u2a + v2);
      ++j;
    }
#pragma unroll 4
    for (; j < 64; j += 2) {
      H4u v; v.v = *(const h4*)&ldsH[V2T + dg * 66 + j];   // b64: j, j+1
      acA0 = acA0 + hmax2z(u2a + v.h[0]);
      acA1 = acA1 + hmax2z(u2a + v.h[1]);
      if (j + 1 >= jsplit) {
        if (j >= jsplit) accb = accb + hmax2z(u2b + v.h[0]);
        accb = accb + hmax2z(u2b + v.h[1]);
      }
    }
    h2 at = acA0 + acA1 + accb;
    ldsf[PART_F + g * 64 + 2 * dg]     = (float)at.x;
    ldsf[PART_F + g * 64 + 2 * dg + 1] = (float)at.y;
  }
  __syncthreads();

  // ------- fused tail (waves 0-9): reduce+combo_sum, softmax, store ---------
  if (tid < 640) {
    const int f = __builtin_amdgcn_readfirstlane((int)(tid >> 6));
    const int l = tid & 63;
    // (1) Hsum reduce along l=d, then butterfly to CS[f] in every lane
    float h = 0.f;
#pragma unroll
    for (int g2 = 0; g2 < 32; ++g2) h += ldsf[PART_F + g2 * 64 + l];
    float p = h * comb_w2[l * F + f];
#pragma unroll
    for (int off = 1; off < 64; off <<= 1) p += __shfl_xor(p, off, 64);
    const float cs = fmaf(comb_b2[f], (float)NPAIR, p);
    // (2) per-lane softmax over the 10 raw distances for token s=l
    float dv[10], dmin = 1e30f;
#pragma unroll
    for (int c = 0; c < 10; ++c) { dv[c] = ldsf[DI_F + l * 11 + c]; dmin = fminf(dmin, dv[c]); }
    float sum = 0.f;
#pragma unroll
    for (int c = 0; c < 10; ++c) sum += expf(dmin - dv[c]);
    const float clu = expf(dmin - dv[f]) / sum;
    const float val = (ffreg + cs + clu) * (1.0f / (float)(NPAIR + 2));
    out[(size_t)b * 640 + l * 10 + f] = val;
  }
}

extern "C" void kernel_launch(void* const* d_in, const int* in_sizes, int n_in,
                              void* d_out, int out_size, void* d_ws, size_t ws_size,
                              hipStream_t stream) {
  (void)in_sizes; (void)n_in; (void)d_ws; (void)ws_size; (void)out_size;
  const int*   ids        = (const int*)  d_in[0];
  const float* emb_table  = (const float*)d_in[1];
  const float* comb_w1    = (const float*)d_in[2];
  const float* comb_b1    = (const float*)d_in[3];
  const float* comb_w2    = (const float*)d_in[4];
  const float* comb_b2    = (const float*)d_in[5];
  const float* freq_w1    = (const float*)d_in[6];
  const float* freq_b1    = (const float*)d_in[7];
  const float* freq_w2    = (const float*)d_in[8];
  const float* freq_b2    = (const float*)d_in[9];
  const float* centers    = (const float*)d_in[10];
  const float* cat_freq   = (const float*)d_in[11];
  const float* total_samp = (const float*)d_in[12];
  float* out = (float*)d_out;

  hipLaunchKernelGGL(cat_enc_kernel, dim3(BATCH), dim3(1024), 0, stream,
                     ids, emb_table, comb_w1, comb_b1, comb_w2, comb_b2,
                     freq_w1, freq_b1, freq_w2, freq_b2, centers, cat_freq,
                     total_samp, out);
}